// Round 8
// baseline (223.463 us; speedup 1.0000x reference)
//
#include <hip/hip_runtime.h>
#include <hip/hip_bf16.h>

// Problem constants
#define PP     4096      // P assets
#define BB     2         // batch
#define DD     128       // model dim
#define NH     4         // heads
#define HDIM   32        // head dim
#define MROWS  8192      // B*P
#define MAXN   24        // max neighbors kept (true max is 17)
#define QKVB   512       // qkv tile blocks in fused kernel (MROWS/16)

// ---- ATTRIBUTION INSTRUMENTATION (round 8): repeat each kernel body REP
// times (idempotent, identical stores) so every kernel's dispatch duration
// exceeds the harness's ~40us fill dispatches and appears in rocprof top-5
// with full counters. Per-kernel cost = dispatch_dur / REP. Set to 1 to
// restore production behavior.
#define REP_FUSED 16
#define REP_ATTN  16
#define REP_OPROJ 32

typedef __attribute__((ext_vector_type(8))) short short8;   // 8 bf16 = 4 VGPR
typedef __attribute__((ext_vector_type(4))) float floatx4;  // MFMA acc

__device__ __forceinline__ unsigned short f2bf(float f) {
  __hip_bfloat16 h = __float2bfloat16(f);
  return *reinterpret_cast<unsigned short*>(&h);
}
__device__ __forceinline__ float bf2f(unsigned short u) {
  union { unsigned int i; float f; } c;
  c.i = ((unsigned int)u) << 16;
  return c.f;
}

// Load 8 consecutive f32 and convert to a bf16 short8 fragment.
__device__ __forceinline__ short8 load_frag_f32(const float* p) {
  const float4* p4 = reinterpret_cast<const float4*>(p);
  float4 a = p4[0], b = p4[1];
  short8 r;
  r[0] = (short)f2bf(a.x); r[1] = (short)f2bf(a.y);
  r[2] = (short)f2bf(a.z); r[3] = (short)f2bf(a.w);
  r[4] = (short)f2bf(b.x); r[5] = (short)f2bf(b.y);
  r[6] = (short)f2bf(b.z); r[7] = (short)f2bf(b.w);
  return r;
}

// Mask dtype detection (0 = u8/bool, 1 = 4-byte int/float).
__device__ __forceinline__ int detect_mode(const unsigned char* mask) {
  bool u8ok = true;
#pragma unroll
  for (int p = 1; p <= 3; ++p) {
    size_t f = (size_t)p * PP + p;
    u8ok = u8ok && (mask[f] == 1);
  }
  return u8ok ? 0 : 1;
}

// ---------------------------------------------------------------------------
// Kernel 1 (fused): blocks [0, QKVB) = 16-row QKV MFMA tile;
// blocks [QKVB, QKVB+PP) = compact one mask row each.
__global__ void fused_compact_qkv(const void* __restrict__ mask,
                                  const float* __restrict__ x,
                                  const float* __restrict__ Wq,
                                  const float* __restrict__ Wk,
                                  const float* __restrict__ Wv,
                                  int* __restrict__ nbr_idx,
                                  int* __restrict__ nbr_cnt,
                                  float* __restrict__ Qf,
                                  unsigned short* __restrict__ Kb,
                                  unsigned short* __restrict__ Vb) {
  int t = threadIdx.x;   // 0..255
  int lane = t & 63, wv = t >> 6;

  if (blockIdx.x < QKVB) {
    int lrow = lane & 15;
    int kb = lane >> 4;                 // 0..3
    int row0 = blockIdx.x * 16;
#pragma unroll 1
    for (int rep = 0; rep < REP_FUSED; ++rep) {
      floatx4 acc[3][2];
#pragma unroll
      for (int m = 0; m < 3; ++m)
#pragma unroll
        for (int c = 0; c < 2; ++c) acc[m][c] = (floatx4){0.f, 0.f, 0.f, 0.f};

#pragma unroll
      for (int ks = 0; ks < 4; ++ks) {
        int k0 = ks * 32 + kb * 8;
        short8 a = load_frag_f32(x + (size_t)(row0 + lrow) * DD + k0);
#pragma unroll
        for (int m = 0; m < 3; ++m) {
          const float* W = m == 0 ? Wq : (m == 1 ? Wk : Wv);
#pragma unroll
          for (int c = 0; c < 2; ++c) {
            int col_tile = wv * 2 + c;
            short8 bf = load_frag_f32(W + (size_t)(col_tile * 16 + lrow) * DD + k0);
            acc[m][c] = __builtin_amdgcn_mfma_f32_16x16x32_bf16(a, bf, acc[m][c], 0, 0, 0);
          }
        }
      }
#pragma unroll
      for (int c = 0; c < 2; ++c)
#pragma unroll
        for (int r = 0; r < 4; ++r) {
          size_t off = (size_t)(row0 + kb * 4 + r) * DD + (wv * 2 + c) * 16 + lrow;
          Qf[off] = acc[0][c][r];
          Kb[off] = f2bf(acc[1][c][r]);
          Vb[off] = f2bf(acc[2][c][r]);
        }
    }
    return;
  }

  // ---- compact half
  int p = blockIdx.x - QKVB;
  __shared__ int wsum[4];
#pragma unroll 1
  for (int rep = 0; rep < REP_FUSED; ++rep) {
    int md = detect_mode((const unsigned char*)mask);
    unsigned int bits = 0;  // bit i => column t*16+i is a neighbor

    if (md == 0) {
      uint4 v = reinterpret_cast<const uint4*>((const unsigned char*)mask +
                                               (size_t)p * PP)[t];
      unsigned int w4[4] = {v.x, v.y, v.z, v.w};
#pragma unroll
      for (int wi = 0; wi < 4; ++wi) {
        unsigned int w = w4[wi];
        unsigned int nz = ((((w & 0x7F7F7F7Fu) + 0x7F7F7F7Fu) | w) & 0x80808080u);
        unsigned int xbit = (nz >> 7) & 0x01010101u;
        unsigned int b4 = (xbit | (xbit >> 7) | (xbit >> 14) | (xbit >> 21)) & 0xFu;
        bits |= b4 << (wi * 4);
      }
    } else {
      const uint4* base =
          reinterpret_cast<const uint4*>((const unsigned int*)mask + (size_t)p * PP) +
          t * 4;
#pragma unroll
      for (int c = 0; c < 4; ++c) {
        uint4 v = base[c];
        unsigned int b4 = (v.x ? 1u : 0u) | (v.y ? 2u : 0u) |
                          (v.z ? 4u : 0u) | (v.w ? 8u : 0u);
        bits |= b4 << (c * 4);
      }
    }

    int cnt = __popc(bits);
    int pre = cnt;  // inclusive prefix within wave
#pragma unroll
    for (int d = 1; d < 64; d <<= 1) {
      int tt = __shfl_up(pre, d);
      if (lane >= d) pre += tt;
    }
    if (lane == 63) wsum[wv] = pre;
    __syncthreads();
    int woff = 0;
#pragma unroll
    for (int w = 0; w < 4; ++w)
      if (w < wv) woff += wsum[w];
    int base_pos = woff + pre - cnt;  // exclusive global prefix
    unsigned int m = bits;
    while (m) {
      int b = __ffs(m) - 1;
      m &= m - 1;
      if (base_pos < MAXN) nbr_idx[p * MAXN + base_pos] = t * 16 + b;
      ++base_pos;
    }
    int total = wsum[0] + wsum[1] + wsum[2] + wsum[3];
    int cl = total < MAXN ? total : MAXN;
    if (t == 0) nbr_cnt[p] = cl;
    if (t >= cl && t < MAXN) nbr_idx[p * MAXN + t] = p;  // pad with self
    __syncthreads();  // wsum reuse barrier across reps
  }
}

// ---------------------------------------------------------------------------
// Kernel 2: sparse attention (unchanged math; REP-instrumented).
__global__ void attn_kernel(const float* __restrict__ Qf,
                            const unsigned short* __restrict__ Kb,
                            const unsigned short* __restrict__ Vb,
                            const int* __restrict__ nbr_idx,
                            const int* __restrict__ nbr_cnt,
                            unsigned short* __restrict__ ctxb) {
  int tid = threadIdx.x;
  int r = tid >> 7;                    // 0..1
  int sub = tid & 127;
  int h = sub >> 5, il = sub & 31;
  int row = blockIdx.x * 2 + r;        // 2 | 4096 => no batch straddle
  int b = row >> 12;
  int bBase = b * PP;

  __shared__ int idx_s[2][MAXN];
  __shared__ int cnt_s[2];
  __shared__ float ws_s[2][NH][32];
  if (tid < 2) cnt_s[tid] = nbr_cnt[(blockIdx.x * 2 + tid) & (PP - 1)];
  if (tid >= 128 && tid < 128 + 2 * MAXN) {
    int u = tid - 128;
    idx_s[u / MAXN][u % MAXN] =
        nbr_idx[((blockIdx.x * 2 + u / MAXN) & (PP - 1)) * MAXN + u % MAXN];
  }
  __syncthreads();
  int cnt = cnt_s[r];
  int slot = il < MAXN ? il : MAXN - 1;
  int j = idx_s[r][slot];

#pragma unroll 1
  for (int rep = 0; rep < REP_ATTN; ++rep) {
    // phase 1: il = neighbor slot
    const unsigned short* Kr = Kb + (size_t)(bBase + j) * DD + h * HDIM;
    const float4* Qr = reinterpret_cast<const float4*>(Qf + (size_t)row * DD + h * HDIM);
    float acc = 0.f;
#pragma unroll
    for (int c = 0; c < 4; ++c) {
      short8 kk = *reinterpret_cast<const short8*>(Kr + c * 8);
      float4 q0 = Qr[c * 2], q1 = Qr[c * 2 + 1];
      acc = fmaf(q0.x, bf2f((unsigned short)kk[0]), acc);
      acc = fmaf(q0.y, bf2f((unsigned short)kk[1]), acc);
      acc = fmaf(q0.z, bf2f((unsigned short)kk[2]), acc);
      acc = fmaf(q0.w, bf2f((unsigned short)kk[3]), acc);
      acc = fmaf(q1.x, bf2f((unsigned short)kk[4]), acc);
      acc = fmaf(q1.y, bf2f((unsigned short)kk[5]), acc);
      acc = fmaf(q1.z, bf2f((unsigned short)kk[6]), acc);
      acc = fmaf(q1.w, bf2f((unsigned short)kk[7]), acc);
    }
    float s = (il < cnt) ? acc * 0.17677669529663689f : -1e30f;  // 1/sqrt(32)

    float mx = s;
    mx = fmaxf(mx, __shfl_xor(mx, 16));
    mx = fmaxf(mx, __shfl_xor(mx, 8));
    mx = fmaxf(mx, __shfl_xor(mx, 4));
    mx = fmaxf(mx, __shfl_xor(mx, 2));
    mx = fmaxf(mx, __shfl_xor(mx, 1));
    float w = (il < cnt) ? __expf(s - mx) : 0.f;
    float l = w;
    l += __shfl_xor(l, 16);
    l += __shfl_xor(l, 8);
    l += __shfl_xor(l, 4);
    l += __shfl_xor(l, 2);
    l += __shfl_xor(l, 1);
    ws_s[r][h][il] = w / l;
    __syncthreads();

    // phase 2: il = element e; fixed-trip, all loads independent
    float acc2 = 0.f;
#pragma unroll
    for (int i = 0; i < MAXN; ++i) {
      int jj = idx_s[r][i];
      float wgt = ws_s[r][h][i];
      acc2 = fmaf(wgt, bf2f(Vb[(size_t)(bBase + jj) * DD + h * HDIM + il]), acc2);
    }
    ctxb[(size_t)row * DD + h * HDIM + il] = f2bf(acc2);
    __syncthreads();  // ws_s reuse barrier across reps
  }
}

// ---------------------------------------------------------------------------
// Kernel 3: out = ctx @ Wo^T via MFMA (unchanged math; REP-instrumented).
__global__ void oproj_kernel(const unsigned short* __restrict__ ctxb,
                             const float* __restrict__ Wo,
                             float* __restrict__ out) {
  int tid = threadIdx.x;
  int wv = tid >> 6;
  int lane = tid & 63;
  int lrow = lane & 15;
  int kb = lane >> 4;
  int row0 = blockIdx.x * 16;

#pragma unroll 1
  for (int rep = 0; rep < REP_OPROJ; ++rep) {
    floatx4 acc[2];
    acc[0] = (floatx4){0.f, 0.f, 0.f, 0.f};
    acc[1] = (floatx4){0.f, 0.f, 0.f, 0.f};
#pragma unroll
    for (int ks = 0; ks < 4; ++ks) {
      int k0 = ks * 32 + kb * 8;
      short8 a = *reinterpret_cast<const short8*>(ctxb + (size_t)(row0 + lrow) * DD + k0);
#pragma unroll
      for (int c = 0; c < 2; ++c) {
        int col_tile = wv * 2 + c;
        short8 bf = load_frag_f32(Wo + (size_t)(col_tile * 16 + lrow) * DD + k0);
        acc[c] = __builtin_amdgcn_mfma_f32_16x16x32_bf16(a, bf, acc[c], 0, 0, 0);
      }
    }
#pragma unroll
    for (int c = 0; c < 2; ++c)
#pragma unroll
      for (int r = 0; r < 4; ++r)
        out[(size_t)(row0 + kb * 4 + r) * DD + (wv * 2 + c) * 16 + lrow] = acc[c][r];
  }
}

// ---------------------------------------------------------------------------
extern "C" void kernel_launch(void* const* d_in, const int* in_sizes, int n_in,
                              void* d_out, int out_size, void* d_ws, size_t ws_size,
                              hipStream_t stream) {
  const float* x    = (const float*)d_in[0];
  const float* Wq   = (const float*)d_in[1];
  const float* Wk   = (const float*)d_in[2];
  const float* Wv   = (const float*)d_in[3];
  const float* Wo   = (const float*)d_in[4];
  const void*  mask = d_in[5];
  float* out = (float*)d_out;

  char* ws = (char*)d_ws;
  int* nbr_cnt = (int*)(ws + 0);                          //   16 KB
  int* nbr_idx = (int*)(ws + 16384);                      //  384 KB -> 409600
  float* Qf = (float*)(ws + 409600);                      //    4 MB -> 4603904
  unsigned short* Kb = (unsigned short*)(ws + 4603904);   //    2 MB -> 6701056
  unsigned short* Vb = (unsigned short*)(ws + 6701056);   //    2 MB -> 8798208
  unsigned short* ctxb = (unsigned short*)(ws + 8798208); //    2 MB -> 10895360

  fused_compact_qkv<<<QKVB + PP, 256, 0, stream>>>(
      mask, x, Wq, Wk, Wv, nbr_idx, nbr_cnt, Qf, Kb, Vb);
  attn_kernel<<<MROWS / 2, 256, 0, stream>>>(Qf, Kb, Vb, nbr_idx, nbr_cnt, ctxb);
  oproj_kernel<<<MROWS / 16, 256, 0, stream>>>(ctxb, Wo, out);
}

// Round 9
// 45.865 us; speedup vs baseline: 4.8722x; 4.8722x over previous
//
#include <hip/hip_runtime.h>
#include <hip/hip_bf16.h>

// Problem constants
#define PP     4096      // P assets
#define BB     2         // batch
#define DD     128       // model dim
#define NH     4         // heads
#define HDIM   32        // head dim
#define MROWS  8192      // B*P
#define MAXN   24        // max neighbors kept (true max is 17)
#define QKVB   512       // qkv tile blocks in fused kernel (MROWS/16)

// Attribution findings (round 8, REP-instrumented):
//   fused_compact_qkv ~8.9us (mask is 4-byte/64MB, L3-BW-bound ~7us; qkv hides)
//   attn ~4us, oproj ~2us, harness fill overhead ~31us of dur_us.

typedef __attribute__((ext_vector_type(8))) short short8;   // 8 bf16 = 4 VGPR
typedef __attribute__((ext_vector_type(4))) float floatx4;  // MFMA acc

__device__ __forceinline__ unsigned short f2bf(float f) {
  __hip_bfloat16 h = __float2bfloat16(f);
  return *reinterpret_cast<unsigned short*>(&h);
}
__device__ __forceinline__ float bf2f(unsigned short u) {
  union { unsigned int i; float f; } c;
  c.i = ((unsigned int)u) << 16;
  return c.f;
}

// Load 8 consecutive f32 and convert to a bf16 short8 fragment.
__device__ __forceinline__ short8 load_frag_f32(const float* p) {
  const float4* p4 = reinterpret_cast<const float4*>(p);
  float4 a = p4[0], b = p4[1];
  short8 r;
  r[0] = (short)f2bf(a.x); r[1] = (short)f2bf(a.y);
  r[2] = (short)f2bf(a.z); r[3] = (short)f2bf(a.w);
  r[4] = (short)f2bf(b.x); r[5] = (short)f2bf(b.y);
  r[6] = (short)f2bf(b.z); r[7] = (short)f2bf(b.w);
  return r;
}

// Mask dtype detection (0 = u8/bool, 1 = 4-byte int/float; for 4-byte
// encodings dword!=0 <=> true, so int32 and f32 share a path).
__device__ __forceinline__ int detect_mode(const unsigned char* mask) {
  bool u8ok = true;
#pragma unroll
  for (int p = 1; p <= 3; ++p) {
    size_t f = (size_t)p * PP + p;
    u8ok = u8ok && (mask[f] == 1);
  }
  return u8ok ? 0 : 1;
}

// ---------------------------------------------------------------------------
// Kernel 1 (fused): blocks [0, QKVB) compute a 16-row QKV MFMA tile;
// blocks [QKVB, QKVB+PP) compact one mask row each. The 64 MB mask stream
// overlaps the GEMM instead of serializing in front of it.
__global__ void fused_compact_qkv(const void* __restrict__ mask,
                                  const float* __restrict__ x,
                                  const float* __restrict__ Wq,
                                  const float* __restrict__ Wk,
                                  const float* __restrict__ Wv,
                                  int* __restrict__ nbr_idx,
                                  int* __restrict__ nbr_cnt,
                                  float* __restrict__ Qf,
                                  unsigned short* __restrict__ Kb,
                                  unsigned short* __restrict__ Vb) {
  int t = threadIdx.x;   // 0..255
  int lane = t & 63, wv = t >> 6;

  if (blockIdx.x < QKVB) {
    // ---- QKV tile: 16 rows; wave wv covers cols [wv*32, wv*32+32) of 3 mats.
    // Fragment layout (m89-verified): A(row,k): lane=row+16*(k>>3), elem=k&7;
    // B(col,k): lane=col+16*(k>>3), elem=k&7; D: col=lane&15, row=(lane>>4)*4+r.
    int lrow = lane & 15;
    int kb = lane >> 4;                 // 0..3
    int row0 = blockIdx.x * 16;

    floatx4 acc[3][2];
#pragma unroll
    for (int m = 0; m < 3; ++m)
#pragma unroll
      for (int c = 0; c < 2; ++c) acc[m][c] = (floatx4){0.f, 0.f, 0.f, 0.f};

#pragma unroll
    for (int ks = 0; ks < 4; ++ks) {
      int k0 = ks * 32 + kb * 8;
      short8 a = load_frag_f32(x + (size_t)(row0 + lrow) * DD + k0);
#pragma unroll
      for (int m = 0; m < 3; ++m) {
        const float* W = m == 0 ? Wq : (m == 1 ? Wk : Wv);
#pragma unroll
        for (int c = 0; c < 2; ++c) {
          int col_tile = wv * 2 + c;
          short8 bf = load_frag_f32(W + (size_t)(col_tile * 16 + lrow) * DD + k0);
          acc[m][c] = __builtin_amdgcn_mfma_f32_16x16x32_bf16(a, bf, acc[m][c], 0, 0, 0);
        }
      }
    }
#pragma unroll
    for (int c = 0; c < 2; ++c)
#pragma unroll
      for (int r = 0; r < 4; ++r) {
        size_t off = (size_t)(row0 + kb * 4 + r) * DD + (wv * 2 + c) * 16 + lrow;
        Qf[off] = acc[0][c][r];
        Kb[off] = f2bf(acc[1][c][r]);
        Vb[off] = f2bf(acc[2][c][r]);
      }
    return;
  }

  // ---- compact: one mask row per block (4 waves). Thread t covers elements
  // [t*16, t*16+16); shfl prefix + LDS cross-wave merge orders the scatter.
  // Slots [cnt, MAXN) padded with p (self) so downstream loops are fixed-trip.
  int p = blockIdx.x - QKVB;
  int md = detect_mode((const unsigned char*)mask);
  unsigned int bits = 0;  // bit i => column t*16+i is a neighbor

  if (md == 0) {
    uint4 v = reinterpret_cast<const uint4*>((const unsigned char*)mask +
                                             (size_t)p * PP)[t];
    unsigned int w4[4] = {v.x, v.y, v.z, v.w};
#pragma unroll
    for (int wi = 0; wi < 4; ++wi) {
      unsigned int w = w4[wi];
      unsigned int nz = ((((w & 0x7F7F7F7Fu) + 0x7F7F7F7Fu) | w) & 0x80808080u);
      unsigned int xbit = (nz >> 7) & 0x01010101u;
      unsigned int b4 = (xbit | (xbit >> 7) | (xbit >> 14) | (xbit >> 21)) & 0xFu;
      bits |= b4 << (wi * 4);
    }
  } else {
    const uint4* base =
        reinterpret_cast<const uint4*>((const unsigned int*)mask + (size_t)p * PP) +
        t * 4;
#pragma unroll
    for (int c = 0; c < 4; ++c) {
      uint4 v = base[c];
      unsigned int b4 = (v.x ? 1u : 0u) | (v.y ? 2u : 0u) |
                        (v.z ? 4u : 0u) | (v.w ? 8u : 0u);
      bits |= b4 << (c * 4);
    }
  }

  int cnt = __popc(bits);
  int pre = cnt;  // inclusive prefix within wave
#pragma unroll
  for (int d = 1; d < 64; d <<= 1) {
    int tt = __shfl_up(pre, d);
    if (lane >= d) pre += tt;
  }
  __shared__ int wsum[4];
  if (lane == 63) wsum[wv] = pre;
  __syncthreads();
  int woff = 0;
#pragma unroll
  for (int w = 0; w < 4; ++w)
    if (w < wv) woff += wsum[w];
  int base_pos = woff + pre - cnt;  // exclusive global prefix
  unsigned int m = bits;
  while (m) {
    int b = __ffs(m) - 1;
    m &= m - 1;
    if (base_pos < MAXN) nbr_idx[p * MAXN + base_pos] = t * 16 + b;
    ++base_pos;
  }
  int total = wsum[0] + wsum[1] + wsum[2] + wsum[3];
  int cl = total < MAXN ? total : MAXN;
  if (t == 0) nbr_cnt[p] = cl;
  if (t >= cl && t < MAXN) nbr_idx[p * MAXN + t] = p;  // pad with self
}

// ---------------------------------------------------------------------------
// Kernel 2: sparse attention. Block = 256 thr = 2 rows; per row 128 thr:
// h = (sub>>5), il = sub&31.
// Phase 1: lane (h,il) = whole bf16-K dot for neighbor slot il. Softmax = 10
// shuffles. Phase 2: fixed MAXN-trip unrolled PV gather (padded idx).
__global__ void attn_kernel(const float* __restrict__ Qf,
                            const unsigned short* __restrict__ Kb,
                            const unsigned short* __restrict__ Vb,
                            const int* __restrict__ nbr_idx,
                            const int* __restrict__ nbr_cnt,
                            unsigned short* __restrict__ ctxb) {
  int tid = threadIdx.x;
  int r = tid >> 7;                    // 0..1
  int sub = tid & 127;
  int h = sub >> 5, il = sub & 31;
  int row = blockIdx.x * 2 + r;        // 2 | 4096 => no batch straddle
  int b = row >> 12;
  int bBase = b * PP;

  __shared__ int idx_s[2][MAXN];
  __shared__ int cnt_s[2];
  __shared__ float ws_s[2][NH][32];
  if (tid < 2) cnt_s[tid] = nbr_cnt[(blockIdx.x * 2 + tid) & (PP - 1)];
  if (tid >= 128 && tid < 128 + 2 * MAXN) {
    int u = tid - 128;
    idx_s[u / MAXN][u % MAXN] =
        nbr_idx[((blockIdx.x * 2 + u / MAXN) & (PP - 1)) * MAXN + u % MAXN];
  }
  __syncthreads();
  int cnt = cnt_s[r];

  // phase 1: il = neighbor slot (clamped; loads unconditional, score masked)
  int slot = il < MAXN ? il : MAXN - 1;
  int j = idx_s[r][slot];
  const unsigned short* Kr = Kb + (size_t)(bBase + j) * DD + h * HDIM;
  const float4* Qr = reinterpret_cast<const float4*>(Qf + (size_t)row * DD + h * HDIM);
  float acc = 0.f;
#pragma unroll
  for (int c = 0; c < 4; ++c) {
    short8 kk = *reinterpret_cast<const short8*>(Kr + c * 8);
    float4 q0 = Qr[c * 2], q1 = Qr[c * 2 + 1];
    acc = fmaf(q0.x, bf2f((unsigned short)kk[0]), acc);
    acc = fmaf(q0.y, bf2f((unsigned short)kk[1]), acc);
    acc = fmaf(q0.z, bf2f((unsigned short)kk[2]), acc);
    acc = fmaf(q0.w, bf2f((unsigned short)kk[3]), acc);
    acc = fmaf(q1.x, bf2f((unsigned short)kk[4]), acc);
    acc = fmaf(q1.y, bf2f((unsigned short)kk[5]), acc);
    acc = fmaf(q1.z, bf2f((unsigned short)kk[6]), acc);
    acc = fmaf(q1.w, bf2f((unsigned short)kk[7]), acc);
  }
  float s = (il < cnt) ? acc * 0.17677669529663689f : -1e30f;  // 1/sqrt(32)

  float mx = s;
  mx = fmaxf(mx, __shfl_xor(mx, 16));
  mx = fmaxf(mx, __shfl_xor(mx, 8));
  mx = fmaxf(mx, __shfl_xor(mx, 4));
  mx = fmaxf(mx, __shfl_xor(mx, 2));
  mx = fmaxf(mx, __shfl_xor(mx, 1));
  float w = (il < cnt) ? __expf(s - mx) : 0.f;
  float l = w;
  l += __shfl_xor(l, 16);
  l += __shfl_xor(l, 8);
  l += __shfl_xor(l, 4);
  l += __shfl_xor(l, 2);
  l += __shfl_xor(l, 1);
  ws_s[r][h][il] = w / l;  // cnt>=1 (diagonal) => l>0
  __syncthreads();

  // phase 2: il = element e; fixed-trip, all loads independent
  float acc2 = 0.f;
#pragma unroll
  for (int i = 0; i < MAXN; ++i) {
    int jj = idx_s[r][i];
    float wgt = ws_s[r][h][i];
    acc2 = fmaf(wgt, bf2f(Vb[(size_t)(bBase + jj) * DD + h * HDIM + il]), acc2);
  }
  ctxb[(size_t)row * DD + h * HDIM + il] = f2bf(acc2);
}

// ---------------------------------------------------------------------------
// Kernel 3: out = ctx @ Wo^T via MFMA; Wo read f32, converted in-register.
// Grid 512 blocks; block = 4 waves = 16 rows; wave wv covers cols
// [wv*32, wv*32+32) (8 MFMA).
__global__ void oproj_kernel(const unsigned short* __restrict__ ctxb,
                             const float* __restrict__ Wo,
                             float* __restrict__ out) {
  int tid = threadIdx.x;
  int wv = tid >> 6;
  int lane = tid & 63;
  int lrow = lane & 15;
  int kb = lane >> 4;
  int row0 = blockIdx.x * 16;

  floatx4 acc[2];
  acc[0] = (floatx4){0.f, 0.f, 0.f, 0.f};
  acc[1] = (floatx4){0.f, 0.f, 0.f, 0.f};
#pragma unroll
  for (int ks = 0; ks < 4; ++ks) {
    int k0 = ks * 32 + kb * 8;
    short8 a = *reinterpret_cast<const short8*>(ctxb + (size_t)(row0 + lrow) * DD + k0);
#pragma unroll
    for (int c = 0; c < 2; ++c) {
      int col_tile = wv * 2 + c;
      short8 bf = load_frag_f32(Wo + (size_t)(col_tile * 16 + lrow) * DD + k0);
      acc[c] = __builtin_amdgcn_mfma_f32_16x16x32_bf16(a, bf, acc[c], 0, 0, 0);
    }
  }
#pragma unroll
  for (int c = 0; c < 2; ++c)
#pragma unroll
    for (int r = 0; r < 4; ++r)
      out[(size_t)(row0 + kb * 4 + r) * DD + (wv * 2 + c) * 16 + lrow] = acc[c][r];
}

// ---------------------------------------------------------------------------
extern "C" void kernel_launch(void* const* d_in, const int* in_sizes, int n_in,
                              void* d_out, int out_size, void* d_ws, size_t ws_size,
                              hipStream_t stream) {
  const float* x    = (const float*)d_in[0];
  const float* Wq   = (const float*)d_in[1];
  const float* Wk   = (const float*)d_in[2];
  const float* Wv   = (const float*)d_in[3];
  const float* Wo   = (const float*)d_in[4];
  const void*  mask = d_in[5];
  float* out = (float*)d_out;

  char* ws = (char*)d_ws;
  int* nbr_cnt = (int*)(ws + 0);                          //   16 KB
  int* nbr_idx = (int*)(ws + 16384);                      //  384 KB -> 409600
  float* Qf = (float*)(ws + 409600);                      //    4 MB -> 4603904
  unsigned short* Kb = (unsigned short*)(ws + 4603904);   //    2 MB -> 6701056
  unsigned short* Vb = (unsigned short*)(ws + 6701056);   //    2 MB -> 8798208
  unsigned short* ctxb = (unsigned short*)(ws + 8798208); //    2 MB -> 10895360

  fused_compact_qkv<<<QKVB + PP, 256, 0, stream>>>(
      mask, x, Wq, Wk, Wv, nbr_idx, nbr_cnt, Qf, Kb, Vb);
  attn_kernel<<<MROWS / 2, 256, 0, stream>>>(Qf, Kb, Vb, nbr_idx, nbr_cnt, ctxb);
  oproj_kernel<<<MROWS / 16, 256, 0, stream>>>(ctxb, Wo, out);
}